// Round 1
// baseline (618.338 us; speedup 1.0000x reference)
//
#include <hip/hip_runtime.h>

typedef _Float16 f16x8 __attribute__((ext_vector_type(8)));
typedef float f32x4 __attribute__((ext_vector_type(4)));

#define GLD16(gp, lp) __builtin_amdgcn_global_load_lds(                     \
    (const __attribute__((address_space(1))) void*)(gp),                    \
    (__attribute__((address_space(3))) void*)(lp), 16, 0, 0)

// ---------------------------------------------------------------------------
// Plain NT GEMM: C[M,N] = A[M,K] * B[N,K]^T (+bias). fp16 inputs, fp32 acc.
// MODE 0: fp32 out (+bias).  MODE 1: fp16 out (+bias).
// MODE 2: fp16 out, per-batch transposed (v): out[(b*1024+col)*2048+s],
//         row = b*2048+s  (requires N==1024, batch stride 2048 rows).
// Batched via blockIdx.z with element strides sA,sB,sC.
// ---------------------------------------------------------------------------
template <int MODE>
__global__ __launch_bounds__(256)
void gemm_nt(const _Float16* __restrict__ A, const _Float16* __restrict__ B,
             void* __restrict__ C, const float* __restrict__ bias,
             int M, int N, int K, size_t sA, size_t sB, size_t sC)
{
    __shared__ __align__(16) _Float16 lA[128 * 32];
    __shared__ __align__(16) _Float16 lB[128 * 32];
    const int tid = threadIdx.x, wave = tid >> 6, lane = tid & 63;
    const int z = blockIdx.z;
    const _Float16* Ab = A + (size_t)z * sA;
    const _Float16* Bb = B + (size_t)z * sB;
    const int m0 = blockIdx.y * 128, n0 = blockIdx.x * 128;
    const int wr = (wave >> 1) * 64, wc = (wave & 1) * 64;
    const int srow = wave * 16 + (lane >> 2);   // staging row (chunk j=0)
    const int scb  = (lane & 3) * 16;           // staging byte within 64B row

    const char* gA = (const char*)(Ab + (size_t)(m0 + srow) * K) + scb;
    const char* gB = (const char*)(Bb + (size_t)(n0 + srow) * K) + scb;
    const size_t rstep = (size_t)64 * K * 2;    // +64 rows, bytes
    char* lAb = (char*)lA + wave * 1024;
    char* lBb = (char*)lB + wave * 1024;

    const int fr = lane & 15, kq = (lane >> 4) * 8;
    const _Float16* rA = lA + (wr + fr) * 32 + kq;
    const _Float16* rB = lB + (wc + fr) * 32 + kq;

    const f32x4 zero = {0.f, 0.f, 0.f, 0.f};
    f32x4 acc[4][4];
#pragma unroll
    for (int i = 0; i < 4; ++i)
#pragma unroll
        for (int j = 0; j < 4; ++j) acc[i][j] = zero;

    for (int k0 = 0; k0 < K; k0 += 32) {
        GLD16(gA, lAb); GLD16(gA + rstep, lAb + 4096);
        GLD16(gB, lBb); GLD16(gB + rstep, lBb + 4096);
        gA += 64; gB += 64;
        __syncthreads();
        f16x8 af[4], bf[4];
#pragma unroll
        for (int i = 0; i < 4; ++i) af[i] = *(const f16x8*)(rA + i * 512);
#pragma unroll
        for (int j = 0; j < 4; ++j) bf[j] = *(const f16x8*)(rB + j * 512);
#pragma unroll
        for (int i = 0; i < 4; ++i)
#pragma unroll
            for (int j = 0; j < 4; ++j)
                acc[i][j] = __builtin_amdgcn_mfma_f32_16x16x32_f16(
                    af[i], bf[j], acc[i][j], 0, 0, 0);
        __syncthreads();
    }

    const int r0 = (lane >> 4) * 4;
#pragma unroll
    for (int j = 0; j < 4; ++j) {
        const int col = n0 + wc + j * 16 + fr;
        const float bv = bias ? bias[col] : 0.0f;
#pragma unroll
        for (int i = 0; i < 4; ++i) {
            const int row = m0 + wr + i * 16 + r0;
            if constexpr (MODE == 0) {
                float* p = (float*)C + (size_t)z * sC + (size_t)row * N + col;
                p[0]             = acc[i][j][0] + bv;
                p[(size_t)N]     = acc[i][j][1] + bv;
                p[(size_t)2 * N] = acc[i][j][2] + bv;
                p[(size_t)3 * N] = acc[i][j][3] + bv;
            } else if constexpr (MODE == 1) {
                _Float16* p = (_Float16*)C + (size_t)z * sC + (size_t)row * N + col;
                p[0]             = (_Float16)(acc[i][j][0] + bv);
                p[(size_t)N]     = (_Float16)(acc[i][j][1] + bv);
                p[(size_t)2 * N] = (_Float16)(acc[i][j][2] + bv);
                p[(size_t)3 * N] = (_Float16)(acc[i][j][3] + bv);
            } else {
                const int bb = row >> 11, s = row & 2047;
                _Float16* p = (_Float16*)C + (((size_t)(bb << 10) + col) << 11) + s;
                p[0] = (_Float16)(acc[i][j][0] + bv);
                p[1] = (_Float16)(acc[i][j][1] + bv);
                p[2] = (_Float16)(acc[i][j][2] + bv);
                p[3] = (_Float16)(acc[i][j][3] + bv);
            }
        }
    }
}

// ---------------------------------------------------------------------------
// Split-precision NT GEMM (2-term fp16 "emulated fp32"):
//   A ~ Ah + Al/2048, B ~ Bh + Bl/2048 (Al,Bl are residuals pre-scaled x2048)
//   C = Ah*Bh + (Ah*Bl + Al*Bh)/2048   (Al*Bl term ~2^-22, dropped)
// MODE 0: fp32 out.  MODE 1: split fp16 pair out (Cm=hi, Ca=lo*2048) +bias.
// ---------------------------------------------------------------------------
template <int MODE>
__global__ __launch_bounds__(256)
void gemm_nt_split(const _Float16* __restrict__ Ah, const _Float16* __restrict__ Al,
                   const _Float16* __restrict__ Bh, const _Float16* __restrict__ Bl,
                   void* __restrict__ Cm, _Float16* __restrict__ Ca,
                   const float* __restrict__ bias,
                   int M, int N, int K, size_t sA, size_t sB, size_t sC)
{
    __shared__ __align__(16) _Float16 lAh[128 * 32];
    __shared__ __align__(16) _Float16 lAl[128 * 32];
    __shared__ __align__(16) _Float16 lBh[128 * 32];
    __shared__ __align__(16) _Float16 lBl[128 * 32];
    const int tid = threadIdx.x, wave = tid >> 6, lane = tid & 63;
    const int z = blockIdx.z;
    const int m0 = blockIdx.y * 128, n0 = blockIdx.x * 128;
    const int wr = (wave >> 1) * 64, wc = (wave & 1) * 64;
    const int srow = wave * 16 + (lane >> 2);
    const int scb  = (lane & 3) * 16;

    const char* gAh = (const char*)(Ah + (size_t)z * sA + (size_t)(m0 + srow) * K) + scb;
    const char* gAl = (const char*)(Al + (size_t)z * sA + (size_t)(m0 + srow) * K) + scb;
    const char* gBh = (const char*)(Bh + (size_t)z * sB + (size_t)(n0 + srow) * K) + scb;
    const char* gBl = (const char*)(Bl + (size_t)z * sB + (size_t)(n0 + srow) * K) + scb;
    const size_t rstep = (size_t)64 * K * 2;
    char* lAhb = (char*)lAh + wave * 1024;
    char* lAlb = (char*)lAl + wave * 1024;
    char* lBhb = (char*)lBh + wave * 1024;
    char* lBlb = (char*)lBl + wave * 1024;

    const int fr = lane & 15, kq = (lane >> 4) * 8;
    const _Float16* rAh = lAh + (wr + fr) * 32 + kq;
    const _Float16* rAl = lAl + (wr + fr) * 32 + kq;
    const _Float16* rBh = lBh + (wc + fr) * 32 + kq;
    const _Float16* rBl = lBl + (wc + fr) * 32 + kq;

    const f32x4 zero = {0.f, 0.f, 0.f, 0.f};
    f32x4 acc1[4][4], acc2[4][4];
#pragma unroll
    for (int i = 0; i < 4; ++i)
#pragma unroll
        for (int j = 0; j < 4; ++j) { acc1[i][j] = zero; acc2[i][j] = zero; }

    for (int k0 = 0; k0 < K; k0 += 32) {
        GLD16(gAh, lAhb); GLD16(gAh + rstep, lAhb + 4096);
        GLD16(gAl, lAlb); GLD16(gAl + rstep, lAlb + 4096);
        GLD16(gBh, lBhb); GLD16(gBh + rstep, lBhb + 4096);
        GLD16(gBl, lBlb); GLD16(gBl + rstep, lBlb + 4096);
        gAh += 64; gAl += 64; gBh += 64; gBl += 64;
        __syncthreads();
        f16x8 bh_[4], bl_[4];
#pragma unroll
        for (int j = 0; j < 4; ++j) {
            bh_[j] = *(const f16x8*)(rBh + j * 512);
            bl_[j] = *(const f16x8*)(rBl + j * 512);
        }
#pragma unroll
        for (int i = 0; i < 4; ++i) {
            const f16x8 ah_ = *(const f16x8*)(rAh + i * 512);
            const f16x8 al_ = *(const f16x8*)(rAl + i * 512);
#pragma unroll
            for (int j = 0; j < 4; ++j) {
                acc1[i][j] = __builtin_amdgcn_mfma_f32_16x16x32_f16(ah_, bh_[j], acc1[i][j], 0, 0, 0);
                acc2[i][j] = __builtin_amdgcn_mfma_f32_16x16x32_f16(ah_, bl_[j], acc2[i][j], 0, 0, 0);
                acc2[i][j] = __builtin_amdgcn_mfma_f32_16x16x32_f16(al_, bh_[j], acc2[i][j], 0, 0, 0);
            }
        }
        __syncthreads();
    }

    const int r0 = (lane >> 4) * 4;
    const float inv2048 = 1.0f / 2048.0f;
#pragma unroll
    for (int j = 0; j < 4; ++j) {
        const int col = n0 + wc + j * 16 + fr;
        const float bv = bias ? bias[col] : 0.0f;
#pragma unroll
        for (int i = 0; i < 4; ++i) {
            const int row = m0 + wr + i * 16 + r0;
#pragma unroll
            for (int r = 0; r < 4; ++r) {
                const float val = acc1[i][j][r] + acc2[i][j][r] * inv2048 + bv;
                const size_t idx = (size_t)z * sC + (size_t)(row + r) * N + col;
                if constexpr (MODE == 0) {
                    ((float*)Cm)[idx] = val;
                } else {
                    const _Float16 hv = (_Float16)val;
                    ((_Float16*)Cm)[idx] = hv;
                    Ca[idx] = (_Float16)((val - (float)hv) * 2048.0f);
                }
            }
        }
    }
}

// ---------------------------------------------------------------------------
// fp32 -> fp16 hi/lo split (lo scaled x2048); lo may be null.
// ---------------------------------------------------------------------------
__global__ __launch_bounds__(256)
void cvt_split_f16(const float* __restrict__ in, _Float16* __restrict__ hi,
                   _Float16* __restrict__ lo, int n8)
{
    const int t = blockIdx.x * 256 + threadIdx.x;
    if (t >= n8) return;
    const float4* p = (const float4*)in + (size_t)t * 2;
    const float4 a = p[0], b = p[1];
    const float v[8] = {a.x, a.y, a.z, a.w, b.x, b.y, b.z, b.w};
    f16x8 h, l;
#pragma unroll
    for (int j = 0; j < 8; ++j) {
        const _Float16 hv = (_Float16)v[j];
        h[j] = hv;
        l[j] = (_Float16)((v[j] - (float)hv) * 2048.0f);
    }
    ((f16x8*)hi)[t] = h;
    if (lo) ((f16x8*)lo)[t] = l;
}

// ---------------------------------------------------------------------------
// W[rows,cols] fp32 -> WT[cols,rows] fp16 hi (+ optional lo*2048).
// ---------------------------------------------------------------------------
__global__ __launch_bounds__(256)
void transpose_split(const float* __restrict__ W, _Float16* __restrict__ hiT,
                     _Float16* __restrict__ loT, int rows, int cols)
{
    __shared__ float t[32][33];
    const int c0 = blockIdx.x * 32, r0 = blockIdx.y * 32;
    const int tx = threadIdx.x & 31, ty = threadIdx.x >> 5;
#pragma unroll
    for (int r = ty; r < 32; r += 8)
        t[r][tx] = W[(size_t)(r0 + r) * cols + (c0 + tx)];
    __syncthreads();
#pragma unroll
    for (int r = ty; r < 32; r += 8) {
        const float v = t[tx][r];
        const _Float16 hv = (_Float16)v;
        const size_t idx = (size_t)(c0 + r) * rows + (r0 + tx);
        hiT[idx] = hv;
        if (loT) loT[idx] = (_Float16)((v - (float)hv) * 2048.0f);
    }
}

// ---------------------------------------------------------------------------
// Row softmax: fp32 scores [rows, 2048] -> fp16 probs. One block per row.
// ---------------------------------------------------------------------------
__global__ __launch_bounds__(256)
void softmax_rows(const float* __restrict__ S, _Float16* __restrict__ P)
{
    const int row = blockIdx.x;
    const float* s = S + (size_t)row * 2048 + threadIdx.x * 8;
    float v[8];
    const float4 a = *(const float4*)s;
    const float4 b = *(const float4*)(s + 4);
    v[0] = a.x; v[1] = a.y; v[2] = a.z; v[3] = a.w;
    v[4] = b.x; v[5] = b.y; v[6] = b.z; v[7] = b.w;
    float mx = v[0];
#pragma unroll
    for (int j = 1; j < 8; ++j) mx = fmaxf(mx, v[j]);
    for (int off = 32; off; off >>= 1) mx = fmaxf(mx, __shfl_xor(mx, off, 64));
    __shared__ float redm[4], reds[4];
    const int wv = threadIdx.x >> 6;
    if ((threadIdx.x & 63) == 0) redm[wv] = mx;
    __syncthreads();
    mx = fmaxf(fmaxf(redm[0], redm[1]), fmaxf(redm[2], redm[3]));
    float sum = 0.f;
#pragma unroll
    for (int j = 0; j < 8; ++j) { v[j] = expf(v[j] - mx); sum += v[j]; }
    for (int off = 32; off; off >>= 1) sum += __shfl_xor(sum, off, 64);
    if ((threadIdx.x & 63) == 0) reds[wv] = sum;
    __syncthreads();
    const float inv = 1.0f / (reds[0] + reds[1] + reds[2] + reds[3]);
    f16x8 o;
#pragma unroll
    for (int j = 0; j < 8; ++j) o[j] = (_Float16)(v[j] * inv);
    *(f16x8*)(P + (size_t)row * 2048 + threadIdx.x * 8) = o;
}

// ---------------------------------------------------------------------------
extern "C" void kernel_launch(void* const* d_in, const int* in_sizes, int n_in,
                              void* d_out, int out_size, void* d_ws, size_t ws_size,
                              hipStream_t stream)
{
    (void)in_sizes; (void)n_in; (void)out_size;
    const float* x  = (const float*)d_in[0];
    const float* Wq = (const float*)d_in[1];
    const float* bq = (const float*)d_in[2];
    const float* Wk = (const float*)d_in[3];
    const float* bk = (const float*)d_in[4];
    const float* Wv = (const float*)d_in[5];
    const float* bv = (const float*)d_in[6];
    const float* Wo = (const float*)d_in[7];
    const float* bo = (const float*)d_in[8];
    float* out = (float*)d_out;

    constexpr int S = 2048, D = 1024, H = 1024, NBATCH = 4;
    constexpr size_t M  = (size_t)NBATCH * S;   // 8192
    constexpr size_t SH = (size_t)S * H;        // per-batch q/k/v elems
    constexpr size_t SS = (size_t)S * S;        // per-batch score elems

    char* w = (char*)d_ws;
    size_t off = 0;
    auto alloc = [&](size_t bytes) -> char* {
        char* p = w + off;
        off += (bytes + 255) & ~(size_t)255;
        return p;
    };

    _Float16* xh  = (_Float16*)alloc(M * D * 2);
    _Float16* xl  = (_Float16*)alloc(M * D * 2);
    _Float16* wqh = (_Float16*)alloc((size_t)D * H * 2);
    _Float16* wql = (_Float16*)alloc((size_t)D * H * 2);
    _Float16* wkh = (_Float16*)alloc((size_t)D * H * 2);
    _Float16* wkl = (_Float16*)alloc((size_t)D * H * 2);
    _Float16* wvh = (_Float16*)alloc((size_t)D * H * 2);
    _Float16* woh = (_Float16*)alloc((size_t)H * D * 2);
    _Float16* qhi = (_Float16*)alloc(M * H * 2);
    _Float16* qlo = (_Float16*)alloc(M * H * 2);
    _Float16* khi = (_Float16*)alloc(M * H * 2);
    _Float16* klo = (_Float16*)alloc(M * H * 2);
    _Float16* vT  = (_Float16*)alloc(M * H * 2);
    _Float16* yh  = xh;  // x (hi+lo, 32MB) is dead after projections; y needs 16MB

    // batch-parallel attention if workspace allows (scores fp32 + P fp16 x4)
    int NB = 1;
    if (ws_size >= off + (size_t)4 * SS * 4 + (size_t)4 * SS * 2 + 1024) NB = 4;
    float*    sc = (float*)alloc((size_t)NB * SS * 4);
    _Float16* Ph = (_Float16*)alloc((size_t)NB * SS * 2);

    // ---- convert / transpose / split ----
    cvt_split_f16<<<dim3((unsigned)(M * D / 8 / 256)), 256, 0, stream>>>(
        x, xh, xl, (int)(M * D / 8));
    dim3 tg(H / 32, D / 32);
    transpose_split<<<tg, 256, 0, stream>>>(Wq, wqh, wql, D, H);
    transpose_split<<<tg, 256, 0, stream>>>(Wk, wkh, wkl, D, H);
    transpose_split<<<tg, 256, 0, stream>>>(Wv, wvh, nullptr, D, H);
    transpose_split<<<tg, 256, 0, stream>>>(Wo, woh, nullptr, H, D);

    // ---- projections ----
    gemm_nt_split<1><<<dim3(H / 128, M / 128), 256, 0, stream>>>(
        xh, xl, wqh, wql, qhi, qlo, bq, (int)M, H, D, 0, 0, 0);
    gemm_nt_split<1><<<dim3(H / 128, M / 128), 256, 0, stream>>>(
        xh, xl, wkh, wkl, khi, klo, bk, (int)M, H, D, 0, 0, 0);
    gemm_nt<2><<<dim3(H / 128, M / 128), 256, 0, stream>>>(
        xh, wvh, vT, bv, (int)M, H, D, 0, 0, 0);

    // ---- attention ----
    for (int b0 = 0; b0 < NBATCH; b0 += NB) {
        gemm_nt_split<0><<<dim3(S / 128, S / 128, NB), 256, 0, stream>>>(
            qhi + (size_t)b0 * SH, qlo + (size_t)b0 * SH,
            khi + (size_t)b0 * SH, klo + (size_t)b0 * SH,
            sc, nullptr, nullptr, S, S, H, SH, SH, SS);
        softmax_rows<<<dim3(NB * S), 256, 0, stream>>>(sc, Ph);
        gemm_nt<1><<<dim3(H / 128, S / 128, NB), 256, 0, stream>>>(
            Ph, vT + (size_t)b0 * SH, yh + (size_t)b0 * SH, nullptr,
            S, H, S, SS, SH, SH);
    }

    // ---- output projection ----
    gemm_nt<0><<<dim3(D / 128, M / 128), 256, 0, stream>>>(
        yh, woh, out, bo, (int)M, D, H, 0, 0, 0);
}

// Round 2
// 395.557 us; speedup vs baseline: 1.5632x; 1.5632x over previous
//
#include <hip/hip_runtime.h>

typedef _Float16 f16x8 __attribute__((ext_vector_type(8)));
typedef float f32x4 __attribute__((ext_vector_type(4)));

#define GLD16(gp, lp) __builtin_amdgcn_global_load_lds(                     \
    (const __attribute__((address_space(1))) void*)(gp),                    \
    (__attribute__((address_space(3))) void*)(lp), 16, 0, 0)

// XCD-aware swizzle of the flattened 2D grid (requires nwg % 8 == 0).
__device__ inline void xcd_swizzle(int& bx, int& by) {
    const int nwg = gridDim.x * gridDim.y;
    const int flat = blockIdx.y * gridDim.x + blockIdx.x;
    const int cpx = nwg >> 3;
    const int swz = (flat & 7) * cpx + (flat >> 3);
    bx = swz % gridDim.x;
    by = swz / gridDim.x;
}

// ---------------------------------------------------------------------------
// Plain NT GEMM: C[M,N] = A[M,K] * B[N,K]^T (+bias). fp16 inputs, fp32 acc.
// MODE 0: fp32 out (+bias).  MODE 1: fp16 out (+bias).
// MODE 2: fp16 out, per-batch transposed (v): out[(b*1024+col)*2048+s].
// LDS rows are 64B; chunk c (16B) of row r holds global chunk c^((r>>1)&3)
// (bank-conflict swizzle: pre-swizzled global source + swizzled ds_read).
// ---------------------------------------------------------------------------
template <int MODE>
__global__ __launch_bounds__(256)
void gemm_nt(const _Float16* __restrict__ A, const _Float16* __restrict__ B,
             void* __restrict__ C, const float* __restrict__ bias,
             int M, int N, int K, size_t sA, size_t sB, size_t sC)
{
    __shared__ __align__(16) _Float16 lA[128 * 32];
    __shared__ __align__(16) _Float16 lB[128 * 32];
    const int tid = threadIdx.x, wave = tid >> 6, lane = tid & 63;
    const int z = blockIdx.z;
    int bx, by; xcd_swizzle(bx, by);
    const _Float16* Ab = A + (size_t)z * sA;
    const _Float16* Bb = B + (size_t)z * sB;
    const int m0 = by * 128, n0 = bx * 128;
    const int wr = (wave >> 1) * 64, wc = (wave & 1) * 64;
    const int srow = wave * 16 + (lane >> 2);
    const int scb  = (((lane & 3) ^ ((srow >> 1) & 3))) * 16;

    const char* gA = (const char*)(Ab + (size_t)(m0 + srow) * K) + scb;
    const char* gB = (const char*)(Bb + (size_t)(n0 + srow) * K) + scb;
    const size_t rstep = (size_t)64 * K * 2;
    char* lAb = (char*)lA + wave * 1024;
    char* lBb = (char*)lB + wave * 1024;

    const int fr = lane & 15;
    const int ckq = ((lane >> 4) ^ ((fr >> 1) & 3)) * 8;
    const _Float16* rA = lA + (wr + fr) * 32 + ckq;
    const _Float16* rB = lB + (wc + fr) * 32 + ckq;

    const f32x4 zero = {0.f, 0.f, 0.f, 0.f};
    f32x4 acc[4][4];
#pragma unroll
    for (int i = 0; i < 4; ++i)
#pragma unroll
        for (int j = 0; j < 4; ++j) acc[i][j] = zero;

    for (int k0 = 0; k0 < K; k0 += 32) {
        GLD16(gA, lAb); GLD16(gA + rstep, lAb + 4096);
        GLD16(gB, lBb); GLD16(gB + rstep, lBb + 4096);
        gA += 64; gB += 64;
        __syncthreads();
        f16x8 af[4], bf[4];
#pragma unroll
        for (int i = 0; i < 4; ++i) af[i] = *(const f16x8*)(rA + i * 512);
#pragma unroll
        for (int j = 0; j < 4; ++j) bf[j] = *(const f16x8*)(rB + j * 512);
#pragma unroll
        for (int i = 0; i < 4; ++i)
#pragma unroll
            for (int j = 0; j < 4; ++j)
                acc[i][j] = __builtin_amdgcn_mfma_f32_16x16x32_f16(
                    af[i], bf[j], acc[i][j], 0, 0, 0);
        __syncthreads();
    }

    const int r0 = (lane >> 4) * 4;
#pragma unroll
    for (int j = 0; j < 4; ++j) {
        const int col = n0 + wc + j * 16 + fr;
        const float bv = bias ? bias[col] : 0.0f;
#pragma unroll
        for (int i = 0; i < 4; ++i) {
            const int row = m0 + wr + i * 16 + r0;
            if constexpr (MODE == 0) {
                float* p = (float*)C + (size_t)z * sC + (size_t)row * N + col;
                p[0]             = acc[i][j][0] + bv;
                p[(size_t)N]     = acc[i][j][1] + bv;
                p[(size_t)2 * N] = acc[i][j][2] + bv;
                p[(size_t)3 * N] = acc[i][j][3] + bv;
            } else if constexpr (MODE == 1) {
                _Float16* p = (_Float16*)C + (size_t)z * sC + (size_t)row * N + col;
                p[0]             = (_Float16)(acc[i][j][0] + bv);
                p[(size_t)N]     = (_Float16)(acc[i][j][1] + bv);
                p[(size_t)2 * N] = (_Float16)(acc[i][j][2] + bv);
                p[(size_t)3 * N] = (_Float16)(acc[i][j][3] + bv);
            } else {
                const int bb = row >> 11, s = row & 2047;
                _Float16* p = (_Float16*)C + (((size_t)(bb << 10) + col) << 11) + s;
                p[0] = (_Float16)(acc[i][j][0] + bv);
                p[1] = (_Float16)(acc[i][j][1] + bv);
                p[2] = (_Float16)(acc[i][j][2] + bv);
                p[3] = (_Float16)(acc[i][j][3] + bv);
            }
        }
    }
}

// ---------------------------------------------------------------------------
// Split-precision NT GEMM, SINGLE accumulator (residuals stored UNSCALED):
//   A ~ Ah + Al, B ~ Bh + Bl   (Al,Bl are true fp16 residuals, ~2^-12 |v|)
//   C = Ah*Bh + Ah*Bl + Al*Bh   (Al*Bl ~ 2^-24, dropped)
// MODE 0: fp32 out.  MODE 1: split fp16 pair out (Cm=hi, Ca=residual) +bias.
// ---------------------------------------------------------------------------
template <int MODE>
__global__ __launch_bounds__(256)
void gemm_nt_split(const _Float16* __restrict__ Ah, const _Float16* __restrict__ Al,
                   const _Float16* __restrict__ Bh, const _Float16* __restrict__ Bl,
                   void* __restrict__ Cm, _Float16* __restrict__ Ca,
                   const float* __restrict__ bias,
                   int M, int N, int K, size_t sA, size_t sB, size_t sC)
{
    __shared__ __align__(16) _Float16 lAh[128 * 32];
    __shared__ __align__(16) _Float16 lAl[128 * 32];
    __shared__ __align__(16) _Float16 lBh[128 * 32];
    __shared__ __align__(16) _Float16 lBl[128 * 32];
    const int tid = threadIdx.x, wave = tid >> 6, lane = tid & 63;
    const int z = blockIdx.z;
    int bx, by; xcd_swizzle(bx, by);
    const int m0 = by * 128, n0 = bx * 128;
    const int wr = (wave >> 1) * 64, wc = (wave & 1) * 64;
    const int srow = wave * 16 + (lane >> 2);
    const int scb  = (((lane & 3) ^ ((srow >> 1) & 3))) * 16;

    const char* gAh = (const char*)(Ah + (size_t)z * sA + (size_t)(m0 + srow) * K) + scb;
    const char* gAl = (const char*)(Al + (size_t)z * sA + (size_t)(m0 + srow) * K) + scb;
    const char* gBh = (const char*)(Bh + (size_t)z * sB + (size_t)(n0 + srow) * K) + scb;
    const char* gBl = (const char*)(Bl + (size_t)z * sB + (size_t)(n0 + srow) * K) + scb;
    const size_t rstep = (size_t)64 * K * 2;
    char* lAhb = (char*)lAh + wave * 1024;
    char* lAlb = (char*)lAl + wave * 1024;
    char* lBhb = (char*)lBh + wave * 1024;
    char* lBlb = (char*)lBl + wave * 1024;

    const int fr = lane & 15;
    const int ckq = ((lane >> 4) ^ ((fr >> 1) & 3)) * 8;
    const _Float16* rAh = lAh + (wr + fr) * 32 + ckq;
    const _Float16* rAl = lAl + (wr + fr) * 32 + ckq;
    const _Float16* rBh = lBh + (wc + fr) * 32 + ckq;
    const _Float16* rBl = lBl + (wc + fr) * 32 + ckq;

    const f32x4 zero = {0.f, 0.f, 0.f, 0.f};
    f32x4 acc[4][4];
#pragma unroll
    for (int i = 0; i < 4; ++i)
#pragma unroll
        for (int j = 0; j < 4; ++j) acc[i][j] = zero;

    for (int k0 = 0; k0 < K; k0 += 32) {
        GLD16(gAh, lAhb); GLD16(gAh + rstep, lAhb + 4096);
        GLD16(gAl, lAlb); GLD16(gAl + rstep, lAlb + 4096);
        GLD16(gBh, lBhb); GLD16(gBh + rstep, lBhb + 4096);
        GLD16(gBl, lBlb); GLD16(gBl + rstep, lBlb + 4096);
        gAh += 64; gAl += 64; gBh += 64; gBl += 64;
        __syncthreads();
        f16x8 bh_[4], bl_[4];
#pragma unroll
        for (int j = 0; j < 4; ++j) {
            bh_[j] = *(const f16x8*)(rBh + j * 512);
            bl_[j] = *(const f16x8*)(rBl + j * 512);
        }
#pragma unroll
        for (int i = 0; i < 4; ++i) {
            const f16x8 ah_ = *(const f16x8*)(rAh + i * 512);
            const f16x8 al_ = *(const f16x8*)(rAl + i * 512);
#pragma unroll
            for (int j = 0; j < 4; ++j) {
                acc[i][j] = __builtin_amdgcn_mfma_f32_16x16x32_f16(ah_, bh_[j], acc[i][j], 0, 0, 0);
                acc[i][j] = __builtin_amdgcn_mfma_f32_16x16x32_f16(ah_, bl_[j], acc[i][j], 0, 0, 0);
                acc[i][j] = __builtin_amdgcn_mfma_f32_16x16x32_f16(al_, bh_[j], acc[i][j], 0, 0, 0);
            }
        }
        __syncthreads();
    }

    const int r0 = (lane >> 4) * 4;
#pragma unroll
    for (int j = 0; j < 4; ++j) {
        const int col = n0 + wc + j * 16 + fr;
        const float bv = bias ? bias[col] : 0.0f;
#pragma unroll
        for (int i = 0; i < 4; ++i) {
            const int row = m0 + wr + i * 16 + r0;
#pragma unroll
            for (int r = 0; r < 4; ++r) {
                const float val = acc[i][j][r] + bv;
                const size_t idx = (size_t)z * sC + (size_t)(row + r) * N + col;
                if constexpr (MODE == 0) {
                    ((float*)Cm)[idx] = val;
                } else {
                    const _Float16 hv = (_Float16)val;
                    ((_Float16*)Cm)[idx] = hv;
                    Ca[idx] = (_Float16)(val - (float)hv);
                }
            }
        }
    }
}

// ---------------------------------------------------------------------------
// fp32 -> fp16 hi/lo split (residual UNSCALED); lo may be null.
// ---------------------------------------------------------------------------
__global__ __launch_bounds__(256)
void cvt_split_f16(const float* __restrict__ in, _Float16* __restrict__ hi,
                   _Float16* __restrict__ lo, int n8)
{
    const int t = blockIdx.x * 256 + threadIdx.x;
    if (t >= n8) return;
    const float4* p = (const float4*)in + (size_t)t * 2;
    const float4 a = p[0], b = p[1];
    const float v[8] = {a.x, a.y, a.z, a.w, b.x, b.y, b.z, b.w};
    f16x8 h, l;
#pragma unroll
    for (int j = 0; j < 8; ++j) {
        const _Float16 hv = (_Float16)v[j];
        h[j] = hv;
        l[j] = (_Float16)(v[j] - (float)hv);
    }
    ((f16x8*)hi)[t] = h;
    if (lo) ((f16x8*)lo)[t] = l;
}

// ---------------------------------------------------------------------------
// W[rows,cols] fp32 -> WT[cols,rows] fp16 hi (+ optional UNSCALED residual).
// ---------------------------------------------------------------------------
__global__ __launch_bounds__(256)
void transpose_split(const float* __restrict__ W, _Float16* __restrict__ hiT,
                     _Float16* __restrict__ loT, int rows, int cols)
{
    __shared__ float t[32][33];
    const int c0 = blockIdx.x * 32, r0 = blockIdx.y * 32;
    const int tx = threadIdx.x & 31, ty = threadIdx.x >> 5;
#pragma unroll
    for (int r = ty; r < 32; r += 8)
        t[r][tx] = W[(size_t)(r0 + r) * cols + (c0 + tx)];
    __syncthreads();
#pragma unroll
    for (int r = ty; r < 32; r += 8) {
        const float v = t[tx][r];
        const _Float16 hv = (_Float16)v;
        const size_t idx = (size_t)(c0 + r) * rows + (r0 + tx);
        hiT[idx] = hv;
        if (loT) loT[idx] = (_Float16)(v - (float)hv);
    }
}

// ---------------------------------------------------------------------------
// Row softmax: fp32 scores [rows, 2048] -> fp16 probs. One block per row.
// ---------------------------------------------------------------------------
__global__ __launch_bounds__(256)
void softmax_rows(const float* __restrict__ S, _Float16* __restrict__ P)
{
    const int row = blockIdx.x;
    const float* s = S + (size_t)row * 2048 + threadIdx.x * 8;
    float v[8];
    const float4 a = *(const float4*)s;
    const float4 b = *(const float4*)(s + 4);
    v[0] = a.x; v[1] = a.y; v[2] = a.z; v[3] = a.w;
    v[4] = b.x; v[5] = b.y; v[6] = b.z; v[7] = b.w;
    float mx = v[0];
#pragma unroll
    for (int j = 1; j < 8; ++j) mx = fmaxf(mx, v[j]);
    for (int off = 32; off; off >>= 1) mx = fmaxf(mx, __shfl_xor(mx, off, 64));
    __shared__ float redm[4], reds[4];
    const int wv = threadIdx.x >> 6;
    if ((threadIdx.x & 63) == 0) redm[wv] = mx;
    __syncthreads();
    mx = fmaxf(fmaxf(redm[0], redm[1]), fmaxf(redm[2], redm[3]));
    float sum = 0.f;
#pragma unroll
    for (int j = 0; j < 8; ++j) { v[j] = expf(v[j] - mx); sum += v[j]; }
    for (int off = 32; off; off >>= 1) sum += __shfl_xor(sum, off, 64);
    if ((threadIdx.x & 63) == 0) reds[wv] = sum;
    __syncthreads();
    const float inv = 1.0f / (reds[0] + reds[1] + reds[2] + reds[3]);
    f16x8 o;
#pragma unroll
    for (int j = 0; j < 8; ++j) o[j] = (_Float16)(v[j] * inv);
    *(f16x8*)(P + (size_t)row * 2048 + threadIdx.x * 8) = o;
}

// ---------------------------------------------------------------------------
extern "C" void kernel_launch(void* const* d_in, const int* in_sizes, int n_in,
                              void* d_out, int out_size, void* d_ws, size_t ws_size,
                              hipStream_t stream)
{
    (void)in_sizes; (void)n_in; (void)out_size;
    const float* x  = (const float*)d_in[0];
    const float* Wq = (const float*)d_in[1];
    const float* bq = (const float*)d_in[2];
    const float* Wk = (const float*)d_in[3];
    const float* bk = (const float*)d_in[4];
    const float* Wv = (const float*)d_in[5];
    const float* bv = (const float*)d_in[6];
    const float* Wo = (const float*)d_in[7];
    const float* bo = (const float*)d_in[8];
    float* out = (float*)d_out;

    constexpr int S = 2048, D = 1024, H = 1024, NBATCH = 4;
    constexpr size_t M  = (size_t)NBATCH * S;   // 8192
    constexpr size_t SH = (size_t)S * H;
    constexpr size_t SS = (size_t)S * S;

    char* w = (char*)d_ws;
    size_t off = 0;
    auto alloc = [&](size_t bytes) -> char* {
        char* p = w + off;
        off += (bytes + 255) & ~(size_t)255;
        return p;
    };

    _Float16* xh  = (_Float16*)alloc(M * D * 2);
    _Float16* xl  = (_Float16*)alloc(M * D * 2);
    _Float16* wqh = (_Float16*)alloc((size_t)D * H * 2);
    _Float16* wql = (_Float16*)alloc((size_t)D * H * 2);
    _Float16* wkh = (_Float16*)alloc((size_t)D * H * 2);
    _Float16* wkl = (_Float16*)alloc((size_t)D * H * 2);
    _Float16* wvh = (_Float16*)alloc((size_t)D * H * 2);
    _Float16* woh = (_Float16*)alloc((size_t)H * D * 2);
    _Float16* qhi = (_Float16*)alloc(M * H * 2);
    _Float16* qlo = (_Float16*)alloc(M * H * 2);
    _Float16* khi = (_Float16*)alloc(M * H * 2);
    _Float16* klo = (_Float16*)alloc(M * H * 2);
    _Float16* vT  = (_Float16*)alloc(M * H * 2);
    _Float16* yh  = xh;  // x (hi+lo) dead after projections; reuse for y

    int NB = 1;
    if (ws_size >= off + (size_t)4 * SS * 4 + (size_t)4 * SS * 2 + 1024) NB = 4;
    float*    sc = (float*)alloc((size_t)NB * SS * 4);
    _Float16* Ph = (_Float16*)alloc((size_t)NB * SS * 2);

    // ---- convert / transpose / split ----
    cvt_split_f16<<<dim3((unsigned)(M * D / 8 / 256)), 256, 0, stream>>>(
        x, xh, xl, (int)(M * D / 8));
    dim3 tg(H / 32, D / 32);
    transpose_split<<<tg, 256, 0, stream>>>(Wq, wqh, wql, D, H);
    transpose_split<<<tg, 256, 0, stream>>>(Wk, wkh, wkl, D, H);
    transpose_split<<<tg, 256, 0, stream>>>(Wv, wvh, nullptr, D, H);
    transpose_split<<<tg, 256, 0, stream>>>(Wo, woh, nullptr, H, D);

    // ---- projections ----
    gemm_nt_split<1><<<dim3(H / 128, M / 128), 256, 0, stream>>>(
        xh, xl, wqh, wql, qhi, qlo, bq, (int)M, H, D, 0, 0, 0);
    gemm_nt_split<1><<<dim3(H / 128, M / 128), 256, 0, stream>>>(
        xh, xl, wkh, wkl, khi, klo, bk, (int)M, H, D, 0, 0, 0);
    gemm_nt<2><<<dim3(H / 128, M / 128), 256, 0, stream>>>(
        xh, wvh, vT, bv, (int)M, H, D, 0, 0, 0);

    // ---- attention ----
    for (int b0 = 0; b0 < NBATCH; b0 += NB) {
        gemm_nt_split<0><<<dim3(S / 128, S / 128, NB), 256, 0, stream>>>(
            qhi + (size_t)b0 * SH, qlo + (size_t)b0 * SH,
            khi + (size_t)b0 * SH, klo + (size_t)b0 * SH,
            sc, nullptr, nullptr, S, S, H, SH, SH, SS);
        softmax_rows<<<dim3(NB * S), 256, 0, stream>>>(sc, Ph);
        gemm_nt<1><<<dim3(H / 128, S / 128, NB), 256, 0, stream>>>(
            Ph, vT + (size_t)b0 * SH, yh + (size_t)b0 * SH, nullptr,
            S, H, S, SS, SH, SH);
    }

    // ---- output projection ----
    gemm_nt<0><<<dim3(D / 128, M / 128), 256, 0, stream>>>(
        yh, woh, out, bo, (int)M, D, H, 0, 0, 0);
}

// Round 3
// 349.060 us; speedup vs baseline: 1.7714x; 1.1332x over previous
//
#include <hip/hip_runtime.h>

typedef _Float16 f16x8 __attribute__((ext_vector_type(8)));
typedef float f32x4 __attribute__((ext_vector_type(4)));

#define GLD16(gp, lp) __builtin_amdgcn_global_load_lds(                     \
    (const __attribute__((address_space(1))) void*)(gp),                    \
    (__attribute__((address_space(3))) void*)(lp), 16, 0, 0)

// XCD-aware swizzle of the flattened 2D grid (requires nwg % 8 == 0).
__device__ inline void xcd_swizzle(int& bx, int& by) {
    const int nwg = gridDim.x * gridDim.y;
    const int flat = blockIdx.y * gridDim.x + blockIdx.x;
    const int cpx = nwg >> 3;
    const int swz = (flat & 7) * cpx + (flat >> 3);
    bx = swz % gridDim.x;
    by = swz / gridDim.x;
}

// ---------------------------------------------------------------------------
// Plain NT GEMM: C[M,N] = A[M,K] * B[N,K]^T (+bias). fp16 inputs, fp32 acc.
// MODE 0: fp32 out (+bias).  MODE 1: fp16 out (+bias).
// MODE 2: fp16 out, per-batch transposed (v): out[(b*1024+col)*2048+s].
// LDS rows are 64B; chunk c (16B) of row r holds global chunk c^((r>>1)&3)
// (bank-conflict swizzle: pre-swizzled global source + swizzled ds_read).
// ---------------------------------------------------------------------------
template <int MODE>
__global__ __launch_bounds__(256)
void gemm_nt(const _Float16* __restrict__ A, const _Float16* __restrict__ B,
             void* __restrict__ C, const float* __restrict__ bias,
             int M, int N, int K, size_t sA, size_t sB, size_t sC)
{
    __shared__ __align__(16) _Float16 lA[128 * 32];
    __shared__ __align__(16) _Float16 lB[128 * 32];
    const int tid = threadIdx.x, wave = tid >> 6, lane = tid & 63;
    const int z = blockIdx.z;
    int bx, by; xcd_swizzle(bx, by);
    const _Float16* Ab = A + (size_t)z * sA;
    const _Float16* Bb = B + (size_t)z * sB;
    const int m0 = by * 128, n0 = bx * 128;
    const int wr = (wave >> 1) * 64, wc = (wave & 1) * 64;
    const int srow = wave * 16 + (lane >> 2);
    const int scb  = (((lane & 3) ^ ((srow >> 1) & 3))) * 16;

    const char* gA = (const char*)(Ab + (size_t)(m0 + srow) * K) + scb;
    const char* gB = (const char*)(Bb + (size_t)(n0 + srow) * K) + scb;
    const size_t rstep = (size_t)64 * K * 2;
    char* lAb = (char*)lA + wave * 1024;
    char* lBb = (char*)lB + wave * 1024;

    const int fr = lane & 15;
    const int ckq = ((lane >> 4) ^ ((fr >> 1) & 3)) * 8;
    const _Float16* rA = lA + (wr + fr) * 32 + ckq;
    const _Float16* rB = lB + (wc + fr) * 32 + ckq;

    const f32x4 zero = {0.f, 0.f, 0.f, 0.f};
    f32x4 acc[4][4];
#pragma unroll
    for (int i = 0; i < 4; ++i)
#pragma unroll
        for (int j = 0; j < 4; ++j) acc[i][j] = zero;

    for (int k0 = 0; k0 < K; k0 += 32) {
        GLD16(gA, lAb); GLD16(gA + rstep, lAb + 4096);
        GLD16(gB, lBb); GLD16(gB + rstep, lBb + 4096);
        gA += 64; gB += 64;
        __syncthreads();
        f16x8 af[4], bf[4];
#pragma unroll
        for (int i = 0; i < 4; ++i) af[i] = *(const f16x8*)(rA + i * 512);
#pragma unroll
        for (int j = 0; j < 4; ++j) bf[j] = *(const f16x8*)(rB + j * 512);
#pragma unroll
        for (int i = 0; i < 4; ++i)
#pragma unroll
            for (int j = 0; j < 4; ++j)
                acc[i][j] = __builtin_amdgcn_mfma_f32_16x16x32_f16(
                    af[i], bf[j], acc[i][j], 0, 0, 0);
        __syncthreads();
    }

    const int r0 = (lane >> 4) * 4;
#pragma unroll
    for (int j = 0; j < 4; ++j) {
        const int col = n0 + wc + j * 16 + fr;
        const float bv = bias ? bias[col] : 0.0f;
#pragma unroll
        for (int i = 0; i < 4; ++i) {
            const int row = m0 + wr + i * 16 + r0;
            if constexpr (MODE == 0) {
                float* p = (float*)C + (size_t)z * sC + (size_t)row * N + col;
                p[0]             = acc[i][j][0] + bv;
                p[(size_t)N]     = acc[i][j][1] + bv;
                p[(size_t)2 * N] = acc[i][j][2] + bv;
                p[(size_t)3 * N] = acc[i][j][3] + bv;
            } else if constexpr (MODE == 1) {
                _Float16* p = (_Float16*)C + (size_t)z * sC + (size_t)row * N + col;
                p[0]             = (_Float16)(acc[i][j][0] + bv);
                p[(size_t)N]     = (_Float16)(acc[i][j][1] + bv);
                p[(size_t)2 * N] = (_Float16)(acc[i][j][2] + bv);
                p[(size_t)3 * N] = (_Float16)(acc[i][j][3] + bv);
            } else {
                const int bb = row >> 11, s = row & 2047;
                _Float16* p = (_Float16*)C + (((size_t)(bb << 10) + col) << 11) + s;
                p[0] = (_Float16)(acc[i][j][0] + bv);
                p[1] = (_Float16)(acc[i][j][1] + bv);
                p[2] = (_Float16)(acc[i][j][2] + bv);
                p[3] = (_Float16)(acc[i][j][3] + bv);
            }
        }
    }
}

// ---------------------------------------------------------------------------
// Split-A NT GEMM: A ~ Ah + Al (unscaled fp16 residual), B plain fp16.
//   C = Ah*B + Al*B   (2 MFMA chains, single accumulator)
// MODE 0: fp32 out (+bias).
// MODE 1: fp16 hi out (+bias) + optional unscaled residual Ca.
// ---------------------------------------------------------------------------
template <int MODE>
__global__ __launch_bounds__(256)
void gemm_nt_spa(const _Float16* __restrict__ Ah, const _Float16* __restrict__ Al,
                 const _Float16* __restrict__ B,
                 void* __restrict__ Cm, _Float16* __restrict__ Ca,
                 const float* __restrict__ bias,
                 int M, int N, int K, size_t sA, size_t sB, size_t sC)
{
    __shared__ __align__(16) _Float16 lAh[128 * 32];
    __shared__ __align__(16) _Float16 lAl[128 * 32];
    __shared__ __align__(16) _Float16 lB [128 * 32];
    const int tid = threadIdx.x, wave = tid >> 6, lane = tid & 63;
    const int z = blockIdx.z;
    int bx, by; xcd_swizzle(bx, by);
    const int m0 = by * 128, n0 = bx * 128;
    const int wr = (wave >> 1) * 64, wc = (wave & 1) * 64;
    const int srow = wave * 16 + (lane >> 2);
    const int scb  = (((lane & 3) ^ ((srow >> 1) & 3))) * 16;

    const char* gAh = (const char*)(Ah + (size_t)z * sA + (size_t)(m0 + srow) * K) + scb;
    const char* gAl = (const char*)(Al + (size_t)z * sA + (size_t)(m0 + srow) * K) + scb;
    const char* gB  = (const char*)(B  + (size_t)z * sB + (size_t)(n0 + srow) * K) + scb;
    const size_t rstep = (size_t)64 * K * 2;
    char* lAhb = (char*)lAh + wave * 1024;
    char* lAlb = (char*)lAl + wave * 1024;
    char* lBb  = (char*)lB  + wave * 1024;

    const int fr = lane & 15;
    const int ckq = ((lane >> 4) ^ ((fr >> 1) & 3)) * 8;
    const _Float16* rAh = lAh + (wr + fr) * 32 + ckq;
    const _Float16* rAl = lAl + (wr + fr) * 32 + ckq;
    const _Float16* rB  = lB  + (wc + fr) * 32 + ckq;

    const f32x4 zero = {0.f, 0.f, 0.f, 0.f};
    f32x4 acc[4][4];
#pragma unroll
    for (int i = 0; i < 4; ++i)
#pragma unroll
        for (int j = 0; j < 4; ++j) acc[i][j] = zero;

    for (int k0 = 0; k0 < K; k0 += 32) {
        GLD16(gAh, lAhb); GLD16(gAh + rstep, lAhb + 4096);
        GLD16(gAl, lAlb); GLD16(gAl + rstep, lAlb + 4096);
        GLD16(gB,  lBb);  GLD16(gB  + rstep, lBb  + 4096);
        gAh += 64; gAl += 64; gB += 64;
        __syncthreads();
        f16x8 bf[4];
#pragma unroll
        for (int j = 0; j < 4; ++j) bf[j] = *(const f16x8*)(rB + j * 512);
#pragma unroll
        for (int i = 0; i < 4; ++i) {
            const f16x8 ah_ = *(const f16x8*)(rAh + i * 512);
            const f16x8 al_ = *(const f16x8*)(rAl + i * 512);
#pragma unroll
            for (int j = 0; j < 4; ++j) {
                acc[i][j] = __builtin_amdgcn_mfma_f32_16x16x32_f16(ah_, bf[j], acc[i][j], 0, 0, 0);
                acc[i][j] = __builtin_amdgcn_mfma_f32_16x16x32_f16(al_, bf[j], acc[i][j], 0, 0, 0);
            }
        }
        __syncthreads();
    }

    const int r0 = (lane >> 4) * 4;
#pragma unroll
    for (int j = 0; j < 4; ++j) {
        const int col = n0 + wc + j * 16 + fr;
        const float bv = bias ? bias[col] : 0.0f;
#pragma unroll
        for (int i = 0; i < 4; ++i) {
            const int row = m0 + wr + i * 16 + r0;
#pragma unroll
            for (int r = 0; r < 4; ++r) {
                const float val = acc[i][j][r] + bv;
                const size_t idx = (size_t)z * sC + (size_t)(row + r) * N + col;
                if constexpr (MODE == 0) {
                    ((float*)Cm)[idx] = val;
                } else {
                    const _Float16 hv = (_Float16)val;
                    ((_Float16*)Cm)[idx] = hv;
                    if (Ca) Ca[idx] = (_Float16)(val - (float)hv);
                }
            }
        }
    }
}

// ---------------------------------------------------------------------------
// fp32 -> fp16 hi/lo split (residual UNSCALED); lo may be null.
// ---------------------------------------------------------------------------
__global__ __launch_bounds__(256)
void cvt_split_f16(const float* __restrict__ in, _Float16* __restrict__ hi,
                   _Float16* __restrict__ lo, int n8)
{
    const int t = blockIdx.x * 256 + threadIdx.x;
    if (t >= n8) return;
    const float4* p = (const float4*)in + (size_t)t * 2;
    const float4 a = p[0], b = p[1];
    const float v[8] = {a.x, a.y, a.z, a.w, b.x, b.y, b.z, b.w};
    f16x8 h, l;
#pragma unroll
    for (int j = 0; j < 8; ++j) {
        const _Float16 hv = (_Float16)v[j];
        h[j] = hv;
        l[j] = (_Float16)(v[j] - (float)hv);
    }
    ((f16x8*)hi)[t] = h;
    if (lo) ((f16x8*)lo)[t] = l;
}

// ---------------------------------------------------------------------------
// W[rows,cols] fp32 -> WT[cols,rows] fp16 (hi only).
// ---------------------------------------------------------------------------
__global__ __launch_bounds__(256)
void transpose_f16(const float* __restrict__ W, _Float16* __restrict__ hiT,
                   int rows, int cols)
{
    __shared__ float t[32][33];
    const int c0 = blockIdx.x * 32, r0 = blockIdx.y * 32;
    const int tx = threadIdx.x & 31, ty = threadIdx.x >> 5;
#pragma unroll
    for (int r = ty; r < 32; r += 8)
        t[r][tx] = W[(size_t)(r0 + r) * cols + (c0 + tx)];
    __syncthreads();
#pragma unroll
    for (int r = ty; r < 32; r += 8)
        hiT[(size_t)(c0 + r) * rows + (r0 + tx)] = (_Float16)t[tx][r];
}

// ---------------------------------------------------------------------------
// Row softmax: fp32 scores [rows, 2048] -> fp16 probs. One block per row.
// ---------------------------------------------------------------------------
__global__ __launch_bounds__(256)
void softmax_rows(const float* __restrict__ S, _Float16* __restrict__ P)
{
    const int row = blockIdx.x;
    const float* s = S + (size_t)row * 2048 + threadIdx.x * 8;
    float v[8];
    const float4 a = *(const float4*)s;
    const float4 b = *(const float4*)(s + 4);
    v[0] = a.x; v[1] = a.y; v[2] = a.z; v[3] = a.w;
    v[4] = b.x; v[5] = b.y; v[6] = b.z; v[7] = b.w;
    float mx = v[0];
#pragma unroll
    for (int j = 1; j < 8; ++j) mx = fmaxf(mx, v[j]);
    for (int off = 32; off; off >>= 1) mx = fmaxf(mx, __shfl_xor(mx, off, 64));
    __shared__ float redm[4], reds[4];
    const int wv = threadIdx.x >> 6;
    if ((threadIdx.x & 63) == 0) redm[wv] = mx;
    __syncthreads();
    mx = fmaxf(fmaxf(redm[0], redm[1]), fmaxf(redm[2], redm[3]));
    float sum = 0.f;
#pragma unroll
    for (int j = 0; j < 8; ++j) { v[j] = expf(v[j] - mx); sum += v[j]; }
    for (int off = 32; off; off >>= 1) sum += __shfl_xor(sum, off, 64);
    if ((threadIdx.x & 63) == 0) reds[wv] = sum;
    __syncthreads();
    const float inv = 1.0f / (reds[0] + reds[1] + reds[2] + reds[3]);
    f16x8 o;
#pragma unroll
    for (int j = 0; j < 8; ++j) o[j] = (_Float16)(v[j] * inv);
    *(f16x8*)(P + (size_t)row * 2048 + threadIdx.x * 8) = o;
}

// ---------------------------------------------------------------------------
extern "C" void kernel_launch(void* const* d_in, const int* in_sizes, int n_in,
                              void* d_out, int out_size, void* d_ws, size_t ws_size,
                              hipStream_t stream)
{
    (void)in_sizes; (void)n_in; (void)out_size;
    const float* x  = (const float*)d_in[0];
    const float* Wq = (const float*)d_in[1];
    const float* bq = (const float*)d_in[2];
    const float* Wk = (const float*)d_in[3];
    const float* bk = (const float*)d_in[4];
    const float* Wv = (const float*)d_in[5];
    const float* bv = (const float*)d_in[6];
    const float* Wo = (const float*)d_in[7];
    const float* bo = (const float*)d_in[8];
    float* out = (float*)d_out;

    constexpr int S = 2048, D = 1024, H = 1024, NBATCH = 4;
    constexpr size_t M  = (size_t)NBATCH * S;   // 8192
    constexpr size_t SH = (size_t)S * H;
    constexpr size_t SS = (size_t)S * S;

    char* w = (char*)d_ws;
    size_t off = 0;
    auto alloc = [&](size_t bytes) -> char* {
        char* p = w + off;
        off += (bytes + 255) & ~(size_t)255;
        return p;
    };

    _Float16* xh  = (_Float16*)alloc(M * D * 2);
    _Float16* xl  = (_Float16*)alloc(M * D * 2);
    _Float16* wqh = (_Float16*)alloc((size_t)D * H * 2);
    _Float16* wkh = (_Float16*)alloc((size_t)D * H * 2);
    _Float16* wvh = (_Float16*)alloc((size_t)D * H * 2);
    _Float16* woh = (_Float16*)alloc((size_t)H * D * 2);
    _Float16* qhi = (_Float16*)alloc(M * H * 2);
    _Float16* qlo = (_Float16*)alloc(M * H * 2);
    _Float16* khi = (_Float16*)alloc(M * H * 2);
    _Float16* vT  = (_Float16*)alloc(M * H * 2);
    _Float16* yh  = xh;  // x (hi+lo) dead after projections; reuse for y

    int NB = 1;
    if (ws_size >= off + (size_t)4 * SS * 4 + (size_t)4 * SS * 2 + 1024) NB = 4;
    float*    sc = (float*)alloc((size_t)NB * SS * 4);
    _Float16* Ph = (_Float16*)alloc((size_t)NB * SS * 2);

    // ---- convert / transpose ----
    cvt_split_f16<<<dim3((unsigned)(M * D / 8 / 256)), 256, 0, stream>>>(
        x, xh, xl, (int)(M * D / 8));
    dim3 tg(H / 32, D / 32);
    transpose_f16<<<tg, 256, 0, stream>>>(Wq, wqh, D, H);
    transpose_f16<<<tg, 256, 0, stream>>>(Wk, wkh, D, H);
    transpose_f16<<<tg, 256, 0, stream>>>(Wv, wvh, D, H);
    transpose_f16<<<tg, 256, 0, stream>>>(Wo, woh, H, D);

    // ---- projections (split-x * plain-W) ----
    gemm_nt_spa<1><<<dim3(H / 128, M / 128), 256, 0, stream>>>(
        xh, xl, wqh, qhi, qlo, bq, (int)M, H, D, 0, 0, 0);
    gemm_nt_spa<1><<<dim3(H / 128, M / 128), 256, 0, stream>>>(
        xh, xl, wkh, khi, nullptr, bk, (int)M, H, D, 0, 0, 0);
    gemm_nt<2><<<dim3(H / 128, M / 128), 256, 0, stream>>>(
        xh, wvh, vT, bv, (int)M, H, D, 0, 0, 0);

    // ---- attention ----
    for (int b0 = 0; b0 < NBATCH; b0 += NB) {
        gemm_nt_spa<0><<<dim3(S / 128, S / 128, NB), 256, 0, stream>>>(
            qhi + (size_t)b0 * SH, qlo + (size_t)b0 * SH,
            khi + (size_t)b0 * SH,
            sc, nullptr, nullptr, S, S, H, SH, SH, SS);
        softmax_rows<<<dim3(NB * S), 256, 0, stream>>>(sc, Ph);
        gemm_nt<1><<<dim3(H / 128, S / 128, NB), 256, 0, stream>>>(
            Ph, vT + (size_t)b0 * SH, yh + (size_t)b0 * SH, nullptr,
            S, H, S, SS, SH, SH);
    }

    // ---- output projection ----
    gemm_nt<0><<<dim3(D / 128, M / 128), 256, 0, stream>>>(
        yh, woh, out, bo, (int)M, D, H, 0, 0, 0);
}

// Round 4
// 345.175 us; speedup vs baseline: 1.7914x; 1.0113x over previous
//
#include <hip/hip_runtime.h>

typedef _Float16 f16x8 __attribute__((ext_vector_type(8)));
typedef float f32x4 __attribute__((ext_vector_type(4)));

#define GLD16(gp, lp) __builtin_amdgcn_global_load_lds(                     \
    (const __attribute__((address_space(1))) void*)(gp),                    \
    (__attribute__((address_space(3))) void*)(lp), 16, 0, 0)

// XCD-aware swizzle of the flattened 2D grid (requires nwg % 8 == 0).
__device__ inline void xcd_swizzle(int& bx, int& by) {
    const int nwg = gridDim.x * gridDim.y;
    const int flat = blockIdx.y * gridDim.x + blockIdx.x;
    const int cpx = nwg >> 3;
    const int swz = (flat & 7) * cpx + (flat >> 3);
    bx = swz % gridDim.x;
    by = swz / gridDim.x;
}

// ---------------------------------------------------------------------------
// Plain NT GEMM: C[.,ldc] = A[.,lda-strided rows] * B[.,ldb]^T (+bias).
// fp16 inputs, fp32 acc. Tiles: 128x128, BK=32, 4 waves.
// MODE 0: fp32 out (+bias).  MODE 1: fp16 out (+bias).
// MODE 2: fp16 out, per-batch transposed (v): out[(b*1024+col)*2048+s].
// LDS rows are 64B; chunk c (16B) of row r holds global chunk c^((r>>1)&3).
// ---------------------------------------------------------------------------
template <int MODE>
__global__ __launch_bounds__(256)
void gemm_nt(const _Float16* __restrict__ A, const _Float16* __restrict__ B,
             void* __restrict__ C, const float* __restrict__ bias,
             int K, int lda, int ldb, int ldc, size_t sA, size_t sB, size_t sC)
{
    __shared__ __align__(16) _Float16 lA[128 * 32];
    __shared__ __align__(16) _Float16 lB[128 * 32];
    const int tid = threadIdx.x, wave = tid >> 6, lane = tid & 63;
    const int z = blockIdx.z;
    int bx, by; xcd_swizzle(bx, by);
    const _Float16* Ab = A + (size_t)z * sA;
    const _Float16* Bb = B + (size_t)z * sB;
    const int m0 = by * 128, n0 = bx * 128;
    const int wr = (wave >> 1) * 64, wc = (wave & 1) * 64;
    const int srow = wave * 16 + (lane >> 2);
    const int scb  = (((lane & 3) ^ ((srow >> 1) & 3))) * 16;

    const char* gA = (const char*)(Ab + (size_t)(m0 + srow) * lda) + scb;
    const char* gB = (const char*)(Bb + (size_t)(n0 + srow) * ldb) + scb;
    const size_t rstepA = (size_t)64 * lda * 2;
    const size_t rstepB = (size_t)64 * ldb * 2;
    char* lAb = (char*)lA + wave * 1024;
    char* lBb = (char*)lB + wave * 1024;

    const int fr = lane & 15;
    const int ckq = ((lane >> 4) ^ ((fr >> 1) & 3)) * 8;
    const _Float16* rA = lA + (wr + fr) * 32 + ckq;
    const _Float16* rB = lB + (wc + fr) * 32 + ckq;

    const f32x4 zero = {0.f, 0.f, 0.f, 0.f};
    f32x4 acc[4][4];
#pragma unroll
    for (int i = 0; i < 4; ++i)
#pragma unroll
        for (int j = 0; j < 4; ++j) acc[i][j] = zero;

    for (int k0 = 0; k0 < K; k0 += 32) {
        GLD16(gA, lAb); GLD16(gA + rstepA, lAb + 4096);
        GLD16(gB, lBb); GLD16(gB + rstepB, lBb + 4096);
        gA += 64; gB += 64;
        __syncthreads();
        f16x8 af[4], bf[4];
#pragma unroll
        for (int i = 0; i < 4; ++i) af[i] = *(const f16x8*)(rA + i * 512);
#pragma unroll
        for (int j = 0; j < 4; ++j) bf[j] = *(const f16x8*)(rB + j * 512);
#pragma unroll
        for (int i = 0; i < 4; ++i)
#pragma unroll
            for (int j = 0; j < 4; ++j)
                acc[i][j] = __builtin_amdgcn_mfma_f32_16x16x32_f16(
                    af[i], bf[j], acc[i][j], 0, 0, 0);
        __syncthreads();
    }

    const int r0 = (lane >> 4) * 4;
#pragma unroll
    for (int j = 0; j < 4; ++j) {
        const int col = n0 + wc + j * 16 + fr;
        const float bv = bias ? bias[col] : 0.0f;
#pragma unroll
        for (int i = 0; i < 4; ++i) {
            const int row = m0 + wr + i * 16 + r0;
            if constexpr (MODE == 0) {
                float* p = (float*)C + (size_t)z * sC + (size_t)row * ldc + col;
                p[0]               = acc[i][j][0] + bv;
                p[(size_t)ldc]     = acc[i][j][1] + bv;
                p[(size_t)2 * ldc] = acc[i][j][2] + bv;
                p[(size_t)3 * ldc] = acc[i][j][3] + bv;
            } else if constexpr (MODE == 1) {
                _Float16* p = (_Float16*)C + (size_t)z * sC + (size_t)row * ldc + col;
                p[0]               = (_Float16)(acc[i][j][0] + bv);
                p[(size_t)ldc]     = (_Float16)(acc[i][j][1] + bv);
                p[(size_t)2 * ldc] = (_Float16)(acc[i][j][2] + bv);
                p[(size_t)3 * ldc] = (_Float16)(acc[i][j][3] + bv);
            } else {
                const int bb = row >> 11, s = row & 2047;
                _Float16* p = (_Float16*)C + (((size_t)(bb << 10) + col) << 11) + s;
                p[0] = (_Float16)(acc[i][j][0] + bv);
                p[1] = (_Float16)(acc[i][j][1] + bv);
                p[2] = (_Float16)(acc[i][j][2] + bv);
                p[3] = (_Float16)(acc[i][j][3] + bv);
            }
        }
    }
}

// ---------------------------------------------------------------------------
// Split-A NT GEMM: A ~ Ah + Al (unscaled fp16 residual), B plain fp16.
//   C = Ah*B + Al*B   (2 MFMA chains, single accumulator)
// MODE 0: fp32 out (+bias).
// MODE 1: fp16 hi out (+bias); residual Ca stored only for col < CaCols.
// ---------------------------------------------------------------------------
template <int MODE>
__global__ __launch_bounds__(256)
void gemm_nt_spa(const _Float16* __restrict__ Ah, const _Float16* __restrict__ Al,
                 const _Float16* __restrict__ B,
                 void* __restrict__ Cm, _Float16* __restrict__ Ca,
                 const float* __restrict__ bias,
                 int K, int lda, int ldb, int ldc, int CaCols,
                 size_t sA, size_t sB, size_t sC)
{
    __shared__ __align__(16) _Float16 lAh[128 * 32];
    __shared__ __align__(16) _Float16 lAl[128 * 32];
    __shared__ __align__(16) _Float16 lB [128 * 32];
    const int tid = threadIdx.x, wave = tid >> 6, lane = tid & 63;
    const int z = blockIdx.z;
    int bx, by; xcd_swizzle(bx, by);
    const int m0 = by * 128, n0 = bx * 128;
    const int wr = (wave >> 1) * 64, wc = (wave & 1) * 64;
    const int srow = wave * 16 + (lane >> 2);
    const int scb  = (((lane & 3) ^ ((srow >> 1) & 3))) * 16;

    const char* gAh = (const char*)(Ah + (size_t)z * sA + (size_t)(m0 + srow) * lda) + scb;
    const char* gAl = (const char*)(Al + (size_t)z * sA + (size_t)(m0 + srow) * lda) + scb;
    const char* gB  = (const char*)(B  + (size_t)z * sB + (size_t)(n0 + srow) * ldb) + scb;
    const size_t rstepA = (size_t)64 * lda * 2;
    const size_t rstepB = (size_t)64 * ldb * 2;
    char* lAhb = (char*)lAh + wave * 1024;
    char* lAlb = (char*)lAl + wave * 1024;
    char* lBb  = (char*)lB  + wave * 1024;

    const int fr = lane & 15;
    const int ckq = ((lane >> 4) ^ ((fr >> 1) & 3)) * 8;
    const _Float16* rAh = lAh + (wr + fr) * 32 + ckq;
    const _Float16* rAl = lAl + (wr + fr) * 32 + ckq;
    const _Float16* rB  = lB  + (wc + fr) * 32 + ckq;

    const f32x4 zero = {0.f, 0.f, 0.f, 0.f};
    f32x4 acc[4][4];
#pragma unroll
    for (int i = 0; i < 4; ++i)
#pragma unroll
        for (int j = 0; j < 4; ++j) acc[i][j] = zero;

    for (int k0 = 0; k0 < K; k0 += 32) {
        GLD16(gAh, lAhb); GLD16(gAh + rstepA, lAhb + 4096);
        GLD16(gAl, lAlb); GLD16(gAl + rstepA, lAlb + 4096);
        GLD16(gB,  lBb);  GLD16(gB  + rstepB, lBb  + 4096);
        gAh += 64; gAl += 64; gB += 64;
        __syncthreads();
        f16x8 bf[4];
#pragma unroll
        for (int j = 0; j < 4; ++j) bf[j] = *(const f16x8*)(rB + j * 512);
#pragma unroll
        for (int i = 0; i < 4; ++i) {
            const f16x8 ah_ = *(const f16x8*)(rAh + i * 512);
            const f16x8 al_ = *(const f16x8*)(rAl + i * 512);
#pragma unroll
            for (int j = 0; j < 4; ++j) {
                acc[i][j] = __builtin_amdgcn_mfma_f32_16x16x32_f16(ah_, bf[j], acc[i][j], 0, 0, 0);
                acc[i][j] = __builtin_amdgcn_mfma_f32_16x16x32_f16(al_, bf[j], acc[i][j], 0, 0, 0);
            }
        }
        __syncthreads();
    }

    const int r0 = (lane >> 4) * 4;
#pragma unroll
    for (int j = 0; j < 4; ++j) {
        const int col = n0 + wc + j * 16 + fr;
        const float bv = bias ? bias[col] : 0.0f;
#pragma unroll
        for (int i = 0; i < 4; ++i) {
            const int row = m0 + wr + i * 16 + r0;
#pragma unroll
            for (int r = 0; r < 4; ++r) {
                const float val = acc[i][j][r] + bv;
                const size_t idx = (size_t)z * sC + (size_t)(row + r) * ldc + col;
                if constexpr (MODE == 0) {
                    ((float*)Cm)[idx] = val;
                } else {
                    const _Float16 hv = (_Float16)val;
                    ((_Float16*)Cm)[idx] = hv;
                    if (col < CaCols) Ca[idx] = (_Float16)(val - (float)hv);
                }
            }
        }
    }
}

// ---------------------------------------------------------------------------
// fp32 -> fp16 hi/lo split (residual UNSCALED); lo may be null.
// ---------------------------------------------------------------------------
__global__ __launch_bounds__(256)
void cvt_split_f16(const float* __restrict__ in, _Float16* __restrict__ hi,
                   _Float16* __restrict__ lo, int n8)
{
    const int t = blockIdx.x * 256 + threadIdx.x;
    if (t >= n8) return;
    const float4* p = (const float4*)in + (size_t)t * 2;
    const float4 a = p[0], b = p[1];
    const float v[8] = {a.x, a.y, a.z, a.w, b.x, b.y, b.z, b.w};
    f16x8 h, l;
#pragma unroll
    for (int j = 0; j < 8; ++j) {
        const _Float16 hv = (_Float16)v[j];
        h[j] = hv;
        l[j] = (_Float16)(v[j] - (float)hv);
    }
    ((f16x8*)hi)[t] = h;
    if (lo) ((f16x8*)lo)[t] = l;
}

// ---------------------------------------------------------------------------
// W[rows,cols] fp32 -> WT[cols,rows] fp16 (hi only).
// ---------------------------------------------------------------------------
__global__ __launch_bounds__(256)
void transpose_f16(const float* __restrict__ W, _Float16* __restrict__ hiT,
                   int rows, int cols)
{
    __shared__ float t[32][33];
    const int c0 = blockIdx.x * 32, r0 = blockIdx.y * 32;
    const int tx = threadIdx.x & 31, ty = threadIdx.x >> 5;
#pragma unroll
    for (int r = ty; r < 32; r += 8)
        t[r][tx] = W[(size_t)(r0 + r) * cols + (c0 + tx)];
    __syncthreads();
#pragma unroll
    for (int r = ty; r < 32; r += 8)
        hiT[(size_t)(c0 + r) * rows + (r0 + tx)] = (_Float16)t[tx][r];
}

// ---------------------------------------------------------------------------
// Concatenate two 1024-float bias vectors.
// ---------------------------------------------------------------------------
__global__ __launch_bounds__(256)
void concat_bias(const float* __restrict__ a, const float* __restrict__ b,
                 float* __restrict__ o)
{
    const int t = blockIdx.x * 256 + threadIdx.x;
    o[t] = (t < 1024) ? a[t] : b[t - 1024];
}

// ---------------------------------------------------------------------------
// Row softmax: fp32 scores [rows, 2048] -> fp16 probs. One block per row.
// ---------------------------------------------------------------------------
__global__ __launch_bounds__(256)
void softmax_rows(const float* __restrict__ S, _Float16* __restrict__ P)
{
    const int row = blockIdx.x;
    const float* s = S + (size_t)row * 2048 + threadIdx.x * 8;
    float v[8];
    const float4 a = *(const float4*)s;
    const float4 b = *(const float4*)(s + 4);
    v[0] = a.x; v[1] = a.y; v[2] = a.z; v[3] = a.w;
    v[4] = b.x; v[5] = b.y; v[6] = b.z; v[7] = b.w;
    float mx = v[0];
#pragma unroll
    for (int j = 1; j < 8; ++j) mx = fmaxf(mx, v[j]);
    for (int off = 32; off; off >>= 1) mx = fmaxf(mx, __shfl_xor(mx, off, 64));
    __shared__ float redm[4], reds[4];
    const int wv = threadIdx.x >> 6;
    if ((threadIdx.x & 63) == 0) redm[wv] = mx;
    __syncthreads();
    mx = fmaxf(fmaxf(redm[0], redm[1]), fmaxf(redm[2], redm[3]));
    float sum = 0.f;
#pragma unroll
    for (int j = 0; j < 8; ++j) { v[j] = expf(v[j] - mx); sum += v[j]; }
    for (int off = 32; off; off >>= 1) sum += __shfl_xor(sum, off, 64);
    if ((threadIdx.x & 63) == 0) reds[wv] = sum;
    __syncthreads();
    const float inv = 1.0f / (reds[0] + reds[1] + reds[2] + reds[3]);
    f16x8 o;
#pragma unroll
    for (int j = 0; j < 8; ++j) o[j] = (_Float16)(v[j] * inv);
    *(f16x8*)(P + (size_t)row * 2048 + threadIdx.x * 8) = o;
}

// ---------------------------------------------------------------------------
extern "C" void kernel_launch(void* const* d_in, const int* in_sizes, int n_in,
                              void* d_out, int out_size, void* d_ws, size_t ws_size,
                              hipStream_t stream)
{
    (void)in_sizes; (void)n_in; (void)out_size;
    const float* x  = (const float*)d_in[0];
    const float* Wq = (const float*)d_in[1];
    const float* bq = (const float*)d_in[2];
    const float* Wk = (const float*)d_in[3];
    const float* bk = (const float*)d_in[4];
    const float* Wv = (const float*)d_in[5];
    const float* bv = (const float*)d_in[6];
    const float* Wo = (const float*)d_in[7];
    const float* bo = (const float*)d_in[8];
    float* out = (float*)d_out;

    constexpr int S = 2048, D = 1024, H = 1024, NBATCH = 4;
    constexpr size_t M  = (size_t)NBATCH * S;   // 8192
    constexpr size_t SH = (size_t)S * H;        // per-batch q/k/v elems
    constexpr size_t SS = (size_t)S * S;        // per-batch score elems
    constexpr size_t QK = (size_t)S * 2048;     // per-batch fused qk row-block

    char* w = (char*)d_ws;
    size_t off = 0;
    auto alloc = [&](size_t bytes) -> char* {
        char* p = w + off;
        off += (bytes + 255) & ~(size_t)255;
        return p;
    };

    _Float16* xh   = (_Float16*)alloc(M * D * 2);
    _Float16* xl   = (_Float16*)alloc(M * D * 2);
    _Float16* wqkT = (_Float16*)alloc((size_t)2 * D * H * 2);  // [2048][1024]
    _Float16* wvh  = (_Float16*)alloc((size_t)D * H * 2);
    _Float16* woh  = (_Float16*)alloc((size_t)H * D * 2);
    float*    bqk  = (float*)alloc(2048 * 4);
    _Float16* qkh  = (_Float16*)alloc(M * 2048 * 2);  // [8192][2048] q|k hi
    _Float16* qkl  = (_Float16*)alloc(M * 2048 * 2);  // residual (q cols only)
    _Float16* vT   = (_Float16*)alloc(M * H * 2);
    _Float16* yh   = xh;  // x (hi+lo) dead after projections; reuse for y

    int NB = 1;
    if (ws_size >= off + (size_t)4 * SS * 4 + (size_t)4 * SS * 2 + 1024) NB = 4;
    float*    sc = (float*)alloc((size_t)NB * SS * 4);
    _Float16* Ph = (_Float16*)alloc((size_t)NB * SS * 2);

    // ---- convert / transpose / concat ----
    cvt_split_f16<<<dim3((unsigned)(M * D / 8 / 256)), 256, 0, stream>>>(
        x, xh, xl, (int)(M * D / 8));
    dim3 tg(H / 32, D / 32);
    transpose_f16<<<tg, 256, 0, stream>>>(Wq, wqkT, D, H);
    transpose_f16<<<tg, 256, 0, stream>>>(Wk, wqkT + (size_t)D * H, D, H);
    transpose_f16<<<tg, 256, 0, stream>>>(Wv, wvh, D, H);
    transpose_f16<<<tg, 256, 0, stream>>>(Wo, woh, H, D);
    concat_bias<<<dim3(8), 256, 0, stream>>>(bq, bk, bqk);

    // ---- fused q|k projection: [8192,2048] = (xh+xl)[8192,1024] * WqkT^T ----
    gemm_nt_spa<1><<<dim3(2048 / 128, M / 128), 256, 0, stream>>>(
        xh, xl, wqkT, qkh, qkl, bqk,
        D, D, D, 2048, /*CaCols=*/1024, 0, 0, 0);

    // ---- v projection (transposed out) ----
    gemm_nt<2><<<dim3(H / 128, M / 128), 256, 0, stream>>>(
        xh, wvh, vT, bv, D, D, D, 0, 0, 0, 0);

    // ---- attention ----
    for (int b0 = 0; b0 < NBATCH; b0 += NB) {
        // scores = (qh+ql) * kh^T ; q = qk cols 0..1023, k = qk cols 1024..2047
        gemm_nt_spa<0><<<dim3(S / 128, S / 128, NB), 256, 0, stream>>>(
            qkh + (size_t)b0 * QK, qkl + (size_t)b0 * QK,
            qkh + (size_t)b0 * QK + 1024,
            sc, nullptr, nullptr,
            H, 2048, 2048, S, 0, QK, QK, SS);
        softmax_rows<<<dim3(NB * S), 256, 0, stream>>>(sc, Ph);
        gemm_nt<1><<<dim3(H / 128, S / 128, NB), 256, 0, stream>>>(
            Ph, vT + (size_t)b0 * SH, yh + (size_t)b0 * SH, nullptr,
            S, S, S, H, SS, SH, SH);
    }

    // ---- output projection ----
    gemm_nt<0><<<dim3(D / 128, M / 128), 256, 0, stream>>>(
        yh, woh, out, bo, H, H, H, D, 0, 0, 0);
}